// Round 7
// baseline (1196.199 us; speedup 1.0000x reference)
//
#include <hip/hip_runtime.h>

// GRU fused, round 7: MFMA rewrite.
// R2/R6 showed the allocator refuses to keep 81 weight dwords/thread in arch
// VGPRs (copy per use -> 2.4x inst inflation). MFMA reads B-fragments from
// AGPRs natively, sidestepping the allocator entirely, and does 512 FLOP/inst.
// One wave per 16 batches (128 blocks x 64 thr), no barriers (wave-sync LDS).
// Per step: A = [h_{t-1} | x_t] (K=64, zero-padded), 9 N-tiles of 16 gates:
//   r/z tiles 0..5: full [W_hh|W_ih] fragments (12 MFMA)
//   n-hat tiles 6..8: W_hh-only (6) + W_ih-only (3)  [r multiplies gh_n only]
//   + fused FC y_{t-1} from the same A (2 MFMA, fc_w zero-padded over x part)
// Epilogue: C layout col=lane&15 (gate col), row=4*(lane>>4)+reg (batch);
// lane owns 12 (batch,unit) slots; h_old kept in regs in C-layout; h written
// back to LDS in f16 A-layout (16B-chunk XOR swizzle; b128 reads 2-way=free).

typedef __fp16 h8 __attribute__((ext_vector_type(8)));
typedef float f4 __attribute__((ext_vector_type(4)));

namespace {

constexpr int T = 1024;
constexpr float Lg = 1.44269504088896340736f;   // log2(e)
constexpr float K2 = 2.88539008177792681472f;   // 2*log2(e)

__device__ __forceinline__ float fexp2(float v) { return __builtin_amdgcn_exp2f(v); }
__device__ __forceinline__ float frcp(float v) { return __builtin_amdgcn_rcpf(v); }
__device__ __forceinline__ f4 mfma16(h8 a, h8 b, f4 c) {
  return __builtin_amdgcn_mfma_f32_16x16x32_f16(a, b, c, 0, 0, 0);
}

__global__ __launch_bounds__(64)
__attribute__((amdgpu_waves_per_eu(1, 1)))
void gru_mfma(const float* __restrict__ x, const float* __restrict__ W_ih,
              const float* __restrict__ W_hh, const float* __restrict__ b_ih,
              const float* __restrict__ b_hh, const float* __restrict__ fc_w,
              const float* __restrict__ fc_b, float* __restrict__ y) {
  // hx[m][k]: f16, m=batch 0..15 (128 B rows), k: 0..47 h, 48..53 x, 54..63 pad.
  // 16B-chunk XOR swizzle: chunk i of row m stored at i^(m&7).
  __shared__ __align__(16) unsigned char lds[16 * 128];

  const int l = threadIdx.x;
  const int q = l >> 4, c = l & 15;
  const long bB = (long)blockIdx.x * 16;

  // ---- weight B-fragments: lane holds column n = tile*16+c, k = kb + j ----
  auto mk = [&](int n, int kb, int mode) {
    h8 f;
#pragma unroll
    for (int j = 0; j < 8; ++j) {
      const int k = kb + j;
      float v = 0.0f;
      if (mode == 0)      v = (k < 48) ? W_hh[n * 48 + k]
                              : ((k < 54) ? W_ih[n * 6 + (k - 48)] : 0.0f);
      else if (mode == 1) v = (k < 48) ? W_hh[n * 48 + k] : 0.0f;
      else if (mode == 2) v = (k >= 48 && k < 54) ? W_ih[n * 6 + (k - 48)] : 0.0f;
      else                v = (k < 48) ? fc_w[n * 48 + k] : 0.0f;  // n pre-clamped
      f[j] = (__fp16)v;
    }
    return f;
  };
  const int kb0 = q * 8, kb1 = 32 + q * 8;
  h8 Brz[6][2], Bnh[3][2], Bnx[3], Bfc[2];
#pragma unroll
  for (int t = 0; t < 6; ++t) {
    Brz[t][0] = mk(t * 16 + c, kb0, 0);
    Brz[t][1] = mk(t * 16 + c, kb1, 0);
  }
#pragma unroll
  for (int i = 0; i < 3; ++i) {
    const int n = 96 + i * 16 + c;
    Bnh[i][0] = mk(n, kb0, 1);
    Bnh[i][1] = mk(n, kb1, 1);
    Bnx[i]    = mk(n, kb1, 2);
  }
  {
    const int nf = (c < 6) ? c : 5;     // cols 6..15 compute garbage, never stored
    Bfc[0] = mk(nf, kb0, 3);
    Bfc[1] = mk(nf, kb1, 3);
  }

  // ---- per-lane biases (pre-scaled for exp2 folding) ----
  float brs[3], bzs[3], bhn2[3], bin2[3];
#pragma unroll
  for (int s = 0; s < 3; ++s) {
    const int u = c + 16 * s;
    brs[s]  = -Lg * (b_ih[u] + b_hh[u]);
    bzs[s]  = -Lg * (b_ih[48 + u] + b_hh[48 + u]);
    bhn2[s] = K2 * b_hh[96 + u];
    bin2[s] = K2 * b_ih[96 + u];
  }
  const float fcb = fc_b[(c < 6) ? c : 0];

  // ---- LDS addresses (step-invariant) ----
  const int a0a = c * 128 + ((q ^ (c & 7)) << 4);          // A chunk q   (k 0..31)
  const int a1a = c * 128 + (((4 + q) ^ (c & 7)) << 4);    // A chunk 4+q (k 32..63)
  int hwa[12];
#pragma unroll
  for (int s = 0; s < 3; ++s)
#pragma unroll
    for (int r = 0; r < 4; ++r) {
      const int m = 4 * q + r;
      hwa[s * 4 + r] = m * 128 + ((((c >> 3) + 2 * s) ^ (m & 7)) << 4) + ((c & 7) << 1);
    }

  // ---- x staging: lanes 0..47 own 2 of the 96 (batch,dim) x-values ----
  const bool xd = (l < 48);
  const int i0 = 2 * l, i1 = 2 * l + 1;
  const int xm0 = (i0 / 6) & 15, xq0 = i0 % 6;
  const int xm1 = (i1 / 6) & 15, xq1 = i1 % 6;
  const int xw0 = xm0 * 128 + ((6 ^ (xm0 & 7)) << 4) + (xq0 << 1);
  const int xw1 = xm1 * 128 + ((6 ^ (xm1 & 7)) << 4) + (xq1 << 1);
  const float* px0 = x + (bB + xm0) * (long)T * 6 + xq0;
  const float* px1 = x + (bB + xm1) * (long)T * 6 + xq1;

  // ---- y pointers: lane (q,c), c<6 stores batches 4q..4q+3, dim c ----
  float* yp[4];
#pragma unroll
  for (int r = 0; r < 4; ++r) yp[r] = y + (bB + 4 * q + r) * (long)T * 6 + c;

  // ---- init LDS: zero h (=h_{-1}) and pad, stage x_0 ----
  ((uint4*)lds)[l]      = uint4{0, 0, 0, 0};
  ((uint4*)lds)[l + 64] = uint4{0, 0, 0, 0};
  if (xd) {
    *(__fp16*)(lds + xw0) = (__fp16)px0[0];
    *(__fp16*)(lds + xw1) = (__fp16)px1[0];
  }
  __builtin_amdgcn_wave_barrier();

  float hreg[12] = {};   // h_old in C-layout: slot s*4+r = (batch 4q+r, unit c+16s)

#pragma unroll 1
  for (int t = 0; t <= T; ++t) {
    union { uint4 u; h8 h; } A0, A1;
    A0.u = *(const uint4*)(lds + a0a);
    A1.u = *(const uint4*)(lds + a1a);
    const f4 z4 = {0.0f, 0.0f, 0.0f, 0.0f};

    // fused FC: y_{t-1} from h_{t-1} (x part of A killed by Bfc zeros)
    f4 Cy = mfma16(A0.h, Bfc[0], z4);
    Cy = mfma16(A1.h, Bfc[1], Cy);
    if (t > 0 && c < 6) {
      const long o = (long)(t - 1) * 6;
      yp[0][o] = Cy[0] + fcb; yp[1][o] = Cy[1] + fcb;
      yp[2][o] = Cy[2] + fcb; yp[3][o] = Cy[3] + fcb;
    }

    if (t < T) {
      float xv0 = 0.0f, xv1 = 0.0f;
      if (t + 1 < T && xd) { xv0 = px0[(t + 1) * 6]; xv1 = px1[(t + 1) * 6]; }

      f4 C0 = mfma16(A0.h, Brz[0][0], z4); C0 = mfma16(A1.h, Brz[0][1], C0);
      f4 C1 = mfma16(A0.h, Brz[1][0], z4); C1 = mfma16(A1.h, Brz[1][1], C1);
      f4 C2 = mfma16(A0.h, Brz[2][0], z4); C2 = mfma16(A1.h, Brz[2][1], C2);
      f4 C3 = mfma16(A0.h, Brz[3][0], z4); C3 = mfma16(A1.h, Brz[3][1], C3);
      f4 C4 = mfma16(A0.h, Brz[4][0], z4); C4 = mfma16(A1.h, Brz[4][1], C4);
      f4 C5 = mfma16(A0.h, Brz[5][0], z4); C5 = mfma16(A1.h, Brz[5][1], C5);
      f4 Ch0 = mfma16(A0.h, Bnh[0][0], z4); Ch0 = mfma16(A1.h, Bnh[0][1], Ch0);
      f4 Ch1 = mfma16(A0.h, Bnh[1][0], z4); Ch1 = mfma16(A1.h, Bnh[1][1], Ch1);
      f4 Ch2 = mfma16(A0.h, Bnh[2][0], z4); Ch2 = mfma16(A1.h, Bnh[2][1], Ch2);
      f4 Cx0 = mfma16(A1.h, Bnx[0], z4);
      f4 Cx1 = mfma16(A1.h, Bnx[1], z4);
      f4 Cx2 = mfma16(A1.h, Bnx[2], z4);

#define EPI(s, CR, CZ, CH, CX)                                           \
      _Pragma("unroll")                                                  \
      for (int r = 0; r < 4; ++r) {                                      \
        const float rr = frcp(1.0f + fexp2(fmaf(-Lg, CR[r], brs[s])));   \
        const float zz = frcp(1.0f + fexp2(fmaf(-Lg, CZ[r], bzs[s])));   \
        const float gh2 = fmaf(K2, CH[r], bhn2[s]);                      \
        const float gx2 = fmaf(K2, CX[r], bin2[s]);                      \
        const float ee = fexp2(fmaf(rr, gh2, gx2));                      \
        const float nn = fmaf(-2.0f, frcp(ee + 1.0f), 1.0f);             \
        float hh = hreg[s * 4 + r];                                      \
        hh = fmaf(zz, hh - nn, nn);                                      \
        hreg[s * 4 + r] = hh;                                            \
        *(__fp16*)(lds + hwa[s * 4 + r]) = (__fp16)hh;                   \
      }
      EPI(0, C0, C3, Ch0, Cx0)
      EPI(1, C1, C4, Ch1, Cx1)
      EPI(2, C2, C5, Ch2, Cx2)
#undef EPI

      if (t + 1 < T && xd) {
        *(__fp16*)(lds + xw0) = (__fp16)xv0;
        *(__fp16*)(lds + xw1) = (__fp16)xv1;
      }
    }
    __builtin_amdgcn_wave_barrier();
  }
}

}  // namespace

extern "C" void kernel_launch(void* const* d_in, const int* in_sizes, int n_in,
                              void* d_out, int out_size, void* d_ws, size_t ws_size,
                              hipStream_t stream) {
  const float* x    = (const float*)d_in[0];
  const float* W_ih = (const float*)d_in[1];
  const float* W_hh = (const float*)d_in[2];
  const float* b_ih = (const float*)d_in[3];
  const float* b_hh = (const float*)d_in[4];
  const float* fc_w = (const float*)d_in[5];
  const float* fc_b = (const float*)d_in[6];
  float* yo = (float*)d_out;

  gru_mfma<<<128, 64, 0, stream>>>(x, W_ih, W_hh, b_ih, b_hh, fc_w, fc_b, yo);
}